// Round 6
// baseline (322.206 us; speedup 1.0000x reference)
//
#include <hip/hip_runtime.h>

#define N_NODES 20000
#define N_EDGES 400000
#define NODE_DIM 256
#define HIDDEN 256
#define OUT_DIM 128
#define PROJ_BLOCKS 628   // 157 m-blocks * 4 n-blocks
#define EDGE_GRID 1250    // 25000 groups / 1250 = exactly 20 per block (no tail)

typedef __attribute__((ext_vector_type(8))) short short8;
typedef __attribute__((ext_vector_type(4))) float f32x4;

__device__ inline unsigned short f2bf(float f) {
  union { float f; unsigned u; } v; v.f = f;
  unsigned r = (v.u + 0x7FFFu + ((v.u >> 16) & 1u)) >> 16;
  return (unsigned short)r;
}

// ---------------- Kernel 1: bf16 MFMA proj GEMM (conv pass eliminated).
// C layout (bf16): C[node][half*256 + n64blk + c*4 + t] where h = n64blk + t*16 + c.
// half 0 = x@W_src, half 1 = x@W_dst + b_edge (bias folded here).
__global__ __launch_bounds__(256) void proj_mfma(
    const float* __restrict__ x, const float* __restrict__ We,
    const float* __restrict__ be, unsigned short* __restrict__ C,
    float* __restrict__ partial) {
  const int tid = threadIdx.x;
  if (blockIdx.x == 0) {
    for (int i = tid; i < 4 * HIDDEN; i += 256) partial[i] = 0.f;
  }
  const int bm = blockIdx.x >> 2;
  const int bn = blockIdx.x & 3;
  const int row0 = bm * 128;
  const int col0 = bn * 128;          // 0,128,256,384
  const int half = col0 >> 8;         // 0: W_src, 1: W_dst
  const int ncol0 = col0 & 255;       // 0 or 128 within half
  const int lane = tid & 63, wave = tid >> 6;
  const int q = lane >> 4, c = lane & 15;
  const int wm = wave >> 1, wn = wave & 1;

  __shared__ unsigned short As[128][32];  // [m][k]
  __shared__ unsigned short Bs[128][32];  // [n][k] (transposed W)

  f32x4 acc[4][4];
#pragma unroll
  for (int i = 0; i < 4; ++i)
#pragma unroll
    for (int t = 0; t < 4; ++t) acc[i][t] = (f32x4){0.f, 0.f, 0.f, 0.f};

  const int ar = tid >> 1;            // A stage row 0..127
  const int ak = (tid & 1) * 16;      // A stage k 0/16
  const int bk = tid >> 3;            // B stage k 0..31
  const int bn0 = (tid & 7) * 16;     // B stage n 0..112

  for (int k0 = 0; k0 < NODE_DIM; k0 += 32) {
    {  // A: x rows -> bf16 LDS
      const int r = row0 + ar;
      short8 t0, t1;
      if (r < N_NODES) {
        const float4* src = (const float4*)&x[(size_t)r * NODE_DIM + k0 + ak];
        float4 f0 = src[0], f1 = src[1], f2 = src[2], f3 = src[3];
        t0[0]=f2bf(f0.x); t0[1]=f2bf(f0.y); t0[2]=f2bf(f0.z); t0[3]=f2bf(f0.w);
        t0[4]=f2bf(f1.x); t0[5]=f2bf(f1.y); t0[6]=f2bf(f1.z); t0[7]=f2bf(f1.w);
        t1[0]=f2bf(f2.x); t1[1]=f2bf(f2.y); t1[2]=f2bf(f2.z); t1[3]=f2bf(f2.w);
        t1[4]=f2bf(f3.x); t1[5]=f2bf(f3.y); t1[6]=f2bf(f3.z); t1[7]=f2bf(f3.w);
      } else {
#pragma unroll
        for (int j = 0; j < 8; ++j) { t0[j] = 0; t1[j] = 0; }
      }
      *(short8*)&As[ar][ak] = t0;
      *(short8*)&As[ar][ak + 8] = t1;
    }
    {  // B: We rows -> transposed bf16 LDS
      const float4* src = (const float4*)&We[(size_t)(half * 256 + k0 + bk) * HIDDEN + ncol0 + bn0];
#pragma unroll
      for (int v = 0; v < 4; ++v) {
        float4 f = src[v];
        Bs[bn0 + v * 4 + 0][bk] = f2bf(f.x);
        Bs[bn0 + v * 4 + 1][bk] = f2bf(f.y);
        Bs[bn0 + v * 4 + 2][bk] = f2bf(f.z);
        Bs[bn0 + v * 4 + 3][bk] = f2bf(f.w);
      }
    }
    __syncthreads();
    short8 Af[4], Bf[4];
#pragma unroll
    for (int i = 0; i < 4; ++i) Af[i] = *(const short8*)&As[wm * 64 + i * 16 + c][q * 8];
#pragma unroll
    for (int t = 0; t < 4; ++t) Bf[t] = *(const short8*)&Bs[wn * 64 + t * 16 + c][q * 8];
#pragma unroll
    for (int i = 0; i < 4; ++i)
#pragma unroll
      for (int t = 0; t < 4; ++t)
        acc[i][t] = __builtin_amdgcn_mfma_f32_16x16x32_bf16(Af[i], Bf[t], acc[i][t], 0, 0, 0);
    __syncthreads();
  }

  float biasv[4] = {0.f, 0.f, 0.f, 0.f};
  const int nbase = ncol0 + wn * 64;
  if (half) {
#pragma unroll
    for (int t = 0; t < 4; ++t) biasv[t] = be[nbase + t * 16 + c];
  }
#pragma unroll
  for (int i = 0; i < 4; ++i) {
#pragma unroll
    for (int r = 0; r < 4; ++r) {
      const int node = row0 + wm * 64 + i * 16 + q * 4 + r;
      if (node < N_NODES) {
        ushort4 o;
        o.x = f2bf(acc[i][0][r] + biasv[0]);
        o.y = f2bf(acc[i][1][r] + biasv[1]);
        o.z = f2bf(acc[i][2][r] + biasv[2]);
        o.w = f2bf(acc[i][3][r] + biasv[3]);
        *(ushort4*)&C[(size_t)node * 512 + half * 256 + nbase + c * 4] = o;
      }
    }
  }
}

// ---------------- Kernel 2: MFMA fused gather + attr-GEMM + relu + mean.
// EXACT round-0 loop structure (96.9 us): zero-C MFMA overlaps with gathers;
// base added on VALU after gathers land. Change vs R0: attrs read directly
// as fp32 (no pre-convert pass) and converted in-register with the HW
// packed convert v_cvt_pk_bf16_f32 (2 floats/inst, RNE).
__global__ __launch_bounds__(256) void edge_mfma(
    const unsigned short* __restrict__ C, const int* __restrict__ ei,
    const float* __restrict__ attrs_f,
    const float* __restrict__ We, float* __restrict__ partial) {
  const int tid = threadIdx.x;
  const int lane = tid & 63, wave = tid >> 6;
  const int q = lane >> 4, c = lane & 15;
  const int hb = wave * 64;

  short8 Bf[4];
#pragma unroll
  for (int t = 0; t < 4; ++t) {
    short8 bf;
#pragma unroll
    for (int j = 0; j < 8; ++j) {
      int k = q * 8 + j;
      float w = (k < 16) ? We[(size_t)(512 + k) * HIDDEN + hb + t * 16 + c] : 0.0f;
      bf[j] = (short)f2bf(w);
    }
    Bf[t] = bf;
  }

  f32x4 acc4[4][4];  // [b][t]
#pragma unroll
  for (int b = 0; b < 4; ++b)
#pragma unroll
    for (int t = 0; t < 4; ++t) acc4[b][t] = (f32x4){0.f, 0.f, 0.f, 0.f};

  const f32x4 zero4 = {0.f, 0.f, 0.f, 0.f};
  const int ngroups = N_EDGES / 16;
  for (int g = blockIdx.x; g < ngroups; g += gridDim.x) {
    const int e0 = g * 16;
    const int4 ns4 = *(const int4*)&ei[e0 + q * 4];
    const int4 nd4 = *(const int4*)&ei[N_EDGES + e0 + q * 4];

    short8 Af[4];
    if (q < 2) {
#pragma unroll
      for (int b = 0; b < 4; ++b) {
        const size_t off = ((size_t)b * N_EDGES + e0 + c) * 16 + q * 8;
        const float4 a0 = *(const float4*)&attrs_f[off];
        const float4 a1 = *(const float4*)&attrs_f[off + 4];
        unsigned r0, r1, r2, r3;
        asm("v_cvt_pk_bf16_f32 %0, %1, %2" : "=v"(r0) : "v"(a0.x), "v"(a0.y));
        asm("v_cvt_pk_bf16_f32 %0, %1, %2" : "=v"(r1) : "v"(a0.z), "v"(a0.w));
        asm("v_cvt_pk_bf16_f32 %0, %1, %2" : "=v"(r2) : "v"(a1.x), "v"(a1.y));
        asm("v_cvt_pk_bf16_f32 %0, %1, %2" : "=v"(r3) : "v"(a1.z), "v"(a1.w));
        union { unsigned u[4]; short8 s; } cv;
        cv.u[0] = r0; cv.u[1] = r1; cv.u[2] = r2; cv.u[3] = r3;
        Af[b] = cv.s;
      }
    } else {
      short8 z;
#pragma unroll
      for (int j = 0; j < 8; ++j) z[j] = 0;
#pragma unroll
      for (int b = 0; b < 4; ++b) Af[b] = z;
    }

    f32x4 base4[4];  // [t], component = row r (bias already folded into dst half)
    {
      const int nn[4] = {ns4.x, ns4.y, ns4.z, ns4.w};
      const int dd[4] = {nd4.x, nd4.y, nd4.z, nd4.w};
#pragma unroll
      for (int r = 0; r < 4; ++r) {
        const uint2 s = *(const uint2*)&C[(size_t)nn[r] * 512 + hb + c * 4];
        const uint2 d = *(const uint2*)&C[(size_t)dd[r] * 512 + 256 + hb + c * 4];
        base4[0][r] = __uint_as_float(s.x << 16) + __uint_as_float(d.x << 16);
        base4[1][r] = __uint_as_float(s.x & 0xFFFF0000u) + __uint_as_float(d.x & 0xFFFF0000u);
        base4[2][r] = __uint_as_float(s.y << 16) + __uint_as_float(d.y << 16);
        base4[3][r] = __uint_as_float(s.y & 0xFFFF0000u) + __uint_as_float(d.y & 0xFFFF0000u);
      }
    }

#pragma unroll
    for (int b = 0; b < 4; ++b) {
#pragma unroll
      for (int t = 0; t < 4; ++t) {
        f32x4 S = __builtin_amdgcn_mfma_f32_16x16x32_bf16(Af[b], Bf[t], zero4, 0, 0, 0);
        f32x4 u = S + base4[t];
        u[0] = fmaxf(u[0], 0.f); u[1] = fmaxf(u[1], 0.f);
        u[2] = fmaxf(u[2], 0.f); u[3] = fmaxf(u[3], 0.f);
        acc4[b][t] += u;
      }
    }
  }

#pragma unroll
  for (int b = 0; b < 4; ++b)
#pragma unroll
    for (int t = 0; t < 4; ++t) {
      float v = acc4[b][t][0] + acc4[b][t][1] + acc4[b][t][2] + acc4[b][t][3];
      v += __shfl_xor(v, 16, 64);
      v += __shfl_xor(v, 32, 64);
      if (q == 0) atomicAdd(&partial[b * HIDDEN + hb + t * 16 + c], v);
    }
}

// ---------------- Kernel 3: out[b,o] = (S[b,:]/E) @ W_graph + b_graph
__global__ __launch_bounds__(256) void graph_out(
    const float* __restrict__ partial, const float* __restrict__ Wg,
    const float* __restrict__ bg, float* __restrict__ out) {
  const int o = blockIdx.x;    // 0..127
  const int hh = threadIdx.x;  // 0..255
  const int lane = hh & 63, wave = hh >> 6;
  const float w = Wg[(size_t)hh * OUT_DIM + o];
  float v[4];
#pragma unroll
  for (int b = 0; b < 4; ++b) v[b] = partial[b * HIDDEN + hh] * w;
#pragma unroll
  for (int off = 32; off >= 1; off >>= 1)
#pragma unroll
    for (int b = 0; b < 4; ++b) v[b] += __shfl_down(v[b], off, 64);
  __shared__ float red[4][4];
  if (lane == 0)
#pragma unroll
    for (int b = 0; b < 4; ++b) red[wave][b] = v[b];
  __syncthreads();
  if (hh < 4) {
    float s = red[0][hh] + red[1][hh] + red[2][hh] + red[3][hh];
    out[hh * OUT_DIM + o] = s * (1.0f / (float)N_EDGES) + bg[o];
  }
}

extern "C" void kernel_launch(void* const* d_in, const int* in_sizes, int n_in,
                              void* d_out, int out_size, void* d_ws, size_t ws_size,
                              hipStream_t stream) {
  const float* x  = (const float*)d_in[0];
  const int*   ei = (const int*)d_in[1];
  const float* ea = (const float*)d_in[2];
  const float* We = (const float*)d_in[3];
  const float* be = (const float*)d_in[4];
  const float* Wg = (const float*)d_in[5];
  const float* bg = (const float*)d_in[6];
  float* out = (float*)d_out;

  const size_t C_bytes = (size_t)N_NODES * 512 * 2;         // 20.48 MB
  unsigned short* C = (unsigned short*)d_ws;
  float* partial = (float*)((char*)d_ws + C_bytes);

  proj_mfma<<<PROJ_BLOCKS, 256, 0, stream>>>(x, We, be, C, partial);
  edge_mfma<<<EDGE_GRID, 256, 0, stream>>>(C, ei, ea, We, partial);
  graph_out<<<128, 256, 0, stream>>>(partial, Wg, bg, out);
}

// Round 7
// 274.738 us; speedup vs baseline: 1.1728x; 1.1728x over previous
//
#include <hip/hip_runtime.h>

#define N_NODES 20000
#define N_EDGES 400000
#define NODE_DIM 256
#define HIDDEN 256
#define OUT_DIM 128
#define PROJ_BLOCKS 628   // 157 m-blocks * 4 n-blocks
#define CONV_BLOCKS 1024  // conv overlaps proj in the same dispatch
#define EDGE_GRID 1250    // 25000 groups / 1250 = exactly 20 per block (no tail)

typedef __attribute__((ext_vector_type(8))) short short8;
typedef __attribute__((ext_vector_type(4))) float f32x4;

__device__ inline unsigned short f2bf(float f) {
  union { float f; unsigned u; } v; v.f = f;
  unsigned r = (v.u + 0x7FFFu + ((v.u >> 16) & 1u)) >> 16;
  return (unsigned short)r;
}

// ---------------- Kernel 1: bf16 MFMA proj GEMM + attrs->bf16 convert.
// C layout (bf16): C[node][half*256 + n64blk + c*4 + t] where h = n64blk + t*16 + c.
// half 0 = x@W_src, half 1 = x@W_dst + b_edge (bias folded here).
__global__ __launch_bounds__(256) void proj_mfma(
    const float* __restrict__ x, const float* __restrict__ We,
    const float* __restrict__ be, unsigned short* __restrict__ C,
    float* __restrict__ partial, const float* __restrict__ attrs,
    unsigned short* __restrict__ attrs_bf) {
  const int tid = threadIdx.x;
  if (blockIdx.x >= PROJ_BLOCKS) {
    // convert attrs fp32 -> bf16 (only launched when ws has room)
    const int nt = CONV_BLOCKS * 256;
    const int total4 = 4 * N_EDGES * 16 / 4;
    for (int i = (blockIdx.x - PROJ_BLOCKS) * 256 + tid; i < total4; i += nt) {
      float4 v = ((const float4*)attrs)[i];
      ushort4 o;
      o.x = f2bf(v.x); o.y = f2bf(v.y); o.z = f2bf(v.z); o.w = f2bf(v.w);
      ((ushort4*)attrs_bf)[i] = o;
    }
    return;
  }
  if (blockIdx.x == 0) {
    for (int i = tid; i < 4 * HIDDEN; i += 256) partial[i] = 0.f;
  }
  const int bm = blockIdx.x >> 2;
  const int bn = blockIdx.x & 3;
  const int row0 = bm * 128;
  const int col0 = bn * 128;          // 0,128,256,384
  const int half = col0 >> 8;         // 0: W_src, 1: W_dst
  const int ncol0 = col0 & 255;       // 0 or 128 within half
  const int lane = tid & 63, wave = tid >> 6;
  const int q = lane >> 4, c = lane & 15;
  const int wm = wave >> 1, wn = wave & 1;

  __shared__ unsigned short As[128][32];  // [m][k]
  __shared__ unsigned short Bs[128][32];  // [n][k] (transposed W)

  f32x4 acc[4][4];
#pragma unroll
  for (int i = 0; i < 4; ++i)
#pragma unroll
    for (int t = 0; t < 4; ++t) acc[i][t] = (f32x4){0.f, 0.f, 0.f, 0.f};

  const int ar = tid >> 1;            // A stage row 0..127
  const int ak = (tid & 1) * 16;      // A stage k 0/16
  const int bk = tid >> 3;            // B stage k 0..31
  const int bn0 = (tid & 7) * 16;     // B stage n 0..112

  for (int k0 = 0; k0 < NODE_DIM; k0 += 32) {
    {  // A: x rows -> bf16 LDS
      const int r = row0 + ar;
      short8 t0, t1;
      if (r < N_NODES) {
        const float4* src = (const float4*)&x[(size_t)r * NODE_DIM + k0 + ak];
        float4 f0 = src[0], f1 = src[1], f2 = src[2], f3 = src[3];
        t0[0]=f2bf(f0.x); t0[1]=f2bf(f0.y); t0[2]=f2bf(f0.z); t0[3]=f2bf(f0.w);
        t0[4]=f2bf(f1.x); t0[5]=f2bf(f1.y); t0[6]=f2bf(f1.z); t0[7]=f2bf(f1.w);
        t1[0]=f2bf(f2.x); t1[1]=f2bf(f2.y); t1[2]=f2bf(f2.z); t1[3]=f2bf(f2.w);
        t1[4]=f2bf(f3.x); t1[5]=f2bf(f3.y); t1[6]=f2bf(f3.z); t1[7]=f2bf(f3.w);
      } else {
#pragma unroll
        for (int j = 0; j < 8; ++j) { t0[j] = 0; t1[j] = 0; }
      }
      *(short8*)&As[ar][ak] = t0;
      *(short8*)&As[ar][ak + 8] = t1;
    }
    {  // B: We rows -> transposed bf16 LDS
      const float4* src = (const float4*)&We[(size_t)(half * 256 + k0 + bk) * HIDDEN + ncol0 + bn0];
#pragma unroll
      for (int v = 0; v < 4; ++v) {
        float4 f = src[v];
        Bs[bn0 + v * 4 + 0][bk] = f2bf(f.x);
        Bs[bn0 + v * 4 + 1][bk] = f2bf(f.y);
        Bs[bn0 + v * 4 + 2][bk] = f2bf(f.z);
        Bs[bn0 + v * 4 + 3][bk] = f2bf(f.w);
      }
    }
    __syncthreads();
    short8 Af[4], Bf[4];
#pragma unroll
    for (int i = 0; i < 4; ++i) Af[i] = *(const short8*)&As[wm * 64 + i * 16 + c][q * 8];
#pragma unroll
    for (int t = 0; t < 4; ++t) Bf[t] = *(const short8*)&Bs[wn * 64 + t * 16 + c][q * 8];
#pragma unroll
    for (int i = 0; i < 4; ++i)
#pragma unroll
      for (int t = 0; t < 4; ++t)
        acc[i][t] = __builtin_amdgcn_mfma_f32_16x16x32_bf16(Af[i], Bf[t], acc[i][t], 0, 0, 0);
    __syncthreads();
  }

  float biasv[4] = {0.f, 0.f, 0.f, 0.f};
  const int nbase = ncol0 + wn * 64;
  if (half) {
#pragma unroll
    for (int t = 0; t < 4; ++t) biasv[t] = be[nbase + t * 16 + c];
  }
#pragma unroll
  for (int i = 0; i < 4; ++i) {
#pragma unroll
    for (int r = 0; r < 4; ++r) {
      const int node = row0 + wm * 64 + i * 16 + q * 4 + r;
      if (node < N_NODES) {
        ushort4 o;
        o.x = f2bf(acc[i][0][r] + biasv[0]);
        o.y = f2bf(acc[i][1][r] + biasv[1]);
        o.z = f2bf(acc[i][2][r] + biasv[2]);
        o.w = f2bf(acc[i][3][r] + biasv[3]);
        *(ushort4*)&C[(size_t)node * 512 + half * 256 + nbase + c * 4] = o;
      }
    }
  }
}

// ---------------- Kernel 2: MFMA fused gather + attr-GEMM + relu + mean.
// R0 loop structure (96.9 us) with ONE change: the r-dimension (4 edges of
// the q-group) is summed into the accumulator immediately after relu.
// acc shrinks 64 -> 16 regs/thread (~148 -> ~100 total) so the unified
// VGPR/AGPR file fits 5 waves/SIMD instead of 3: occupancy-driven latency
// hiding for the random gathers.
template <bool PRE>
__global__ __launch_bounds__(256) void edge_mfma(
    const unsigned short* __restrict__ C, const int* __restrict__ ei,
    const float* __restrict__ attrs_f, const unsigned short* __restrict__ attrs_b,
    const float* __restrict__ We, float* __restrict__ partial) {
  const int tid = threadIdx.x;
  const int lane = tid & 63, wave = tid >> 6;
  const int q = lane >> 4, c = lane & 15;
  const int hb = wave * 64;

  short8 Bf[4];
#pragma unroll
  for (int t = 0; t < 4; ++t) {
    short8 bf;
#pragma unroll
    for (int j = 0; j < 8; ++j) {
      int k = q * 8 + j;
      float w = (k < 16) ? We[(size_t)(512 + k) * HIDDEN + hb + t * 16 + c] : 0.0f;
      bf[j] = (short)f2bf(w);
    }
    Bf[t] = bf;
  }

  f32x4 accs[4];  // [b], component index = t  (16 accumulator regs total)
#pragma unroll
  for (int b = 0; b < 4; ++b) accs[b] = (f32x4){0.f, 0.f, 0.f, 0.f};

  const f32x4 zero4 = {0.f, 0.f, 0.f, 0.f};
  const int ngroups = N_EDGES / 16;
  for (int g = blockIdx.x; g < ngroups; g += gridDim.x) {
    const int e0 = g * 16;
    const int4 ns4 = *(const int4*)&ei[e0 + q * 4];
    const int4 nd4 = *(const int4*)&ei[N_EDGES + e0 + q * 4];

    short8 Af[4];
    if (PRE) {
      if (q < 2) {
#pragma unroll
        for (int b = 0; b < 4; ++b)
          Af[b] = *(const short8*)&attrs_b[((size_t)b * N_EDGES + e0 + c) * 16 + q * 8];
      } else {
        short8 z;
#pragma unroll
        for (int j = 0; j < 8; ++j) z[j] = 0;
#pragma unroll
        for (int b = 0; b < 4; ++b) Af[b] = z;
      }
    } else {
      if (q < 2) {
#pragma unroll
        for (int b = 0; b < 4; ++b) {
          const size_t off = ((size_t)b * N_EDGES + e0 + c) * 16 + q * 8;
          const float4 a0 = *(const float4*)&attrs_f[off];
          const float4 a1 = *(const float4*)&attrs_f[off + 4];
          short8 af;
          af[0]=f2bf(a0.x); af[1]=f2bf(a0.y); af[2]=f2bf(a0.z); af[3]=f2bf(a0.w);
          af[4]=f2bf(a1.x); af[5]=f2bf(a1.y); af[6]=f2bf(a1.z); af[7]=f2bf(a1.w);
          Af[b] = af;
        }
      } else {
        short8 z;
#pragma unroll
        for (int j = 0; j < 8; ++j) z[j] = 0;
#pragma unroll
        for (int b = 0; b < 4; ++b) Af[b] = z;
      }
    }

    f32x4 base4[4];  // [t], component = row r (bias already folded into dst half)
    {
      const int nn[4] = {ns4.x, ns4.y, ns4.z, ns4.w};
      const int dd[4] = {nd4.x, nd4.y, nd4.z, nd4.w};
#pragma unroll
      for (int r = 0; r < 4; ++r) {
        const uint2 s = *(const uint2*)&C[(size_t)nn[r] * 512 + hb + c * 4];
        const uint2 d = *(const uint2*)&C[(size_t)dd[r] * 512 + 256 + hb + c * 4];
        base4[0][r] = __uint_as_float(s.x << 16) + __uint_as_float(d.x << 16);
        base4[1][r] = __uint_as_float(s.x & 0xFFFF0000u) + __uint_as_float(d.x & 0xFFFF0000u);
        base4[2][r] = __uint_as_float(s.y << 16) + __uint_as_float(d.y << 16);
        base4[3][r] = __uint_as_float(s.y & 0xFFFF0000u) + __uint_as_float(d.y & 0xFFFF0000u);
      }
    }

#pragma unroll
    for (int b = 0; b < 4; ++b) {
#pragma unroll
      for (int t = 0; t < 4; ++t) {
        f32x4 S = __builtin_amdgcn_mfma_f32_16x16x32_bf16(Af[b], Bf[t], zero4, 0, 0, 0);
        f32x4 u = S + base4[t];
        u[0] = fmaxf(u[0], 0.f); u[1] = fmaxf(u[1], 0.f);
        u[2] = fmaxf(u[2], 0.f); u[3] = fmaxf(u[3], 0.f);
        // fold the 4 edges (rows r) of this q-group into one scalar now:
        accs[b][t] += (u[0] + u[1]) + (u[2] + u[3]);
      }
    }
  }

#pragma unroll
  for (int b = 0; b < 4; ++b)
#pragma unroll
    for (int t = 0; t < 4; ++t) {
      float v = accs[b][t];
      v += __shfl_xor(v, 16, 64);
      v += __shfl_xor(v, 32, 64);
      if (q == 0) atomicAdd(&partial[b * HIDDEN + hb + t * 16 + c], v);
    }
}

// ---------------- Kernel 3: out[b,o] = (S[b,:]/E) @ W_graph + b_graph
__global__ __launch_bounds__(256) void graph_out(
    const float* __restrict__ partial, const float* __restrict__ Wg,
    const float* __restrict__ bg, float* __restrict__ out) {
  const int o = blockIdx.x;    // 0..127
  const int hh = threadIdx.x;  // 0..255
  const int lane = hh & 63, wave = hh >> 6;
  const float w = Wg[(size_t)hh * OUT_DIM + o];
  float v[4];
#pragma unroll
  for (int b = 0; b < 4; ++b) v[b] = partial[b * HIDDEN + hh] * w;
#pragma unroll
  for (int off = 32; off >= 1; off >>= 1)
#pragma unroll
    for (int b = 0; b < 4; ++b) v[b] += __shfl_down(v[b], off, 64);
  __shared__ float red[4][4];
  if (lane == 0)
#pragma unroll
    for (int b = 0; b < 4; ++b) red[wave][b] = v[b];
  __syncthreads();
  if (hh < 4) {
    float s = red[0][hh] + red[1][hh] + red[2][hh] + red[3][hh];
    out[hh * OUT_DIM + o] = s * (1.0f / (float)N_EDGES) + bg[o];
  }
}

extern "C" void kernel_launch(void* const* d_in, const int* in_sizes, int n_in,
                              void* d_out, int out_size, void* d_ws, size_t ws_size,
                              hipStream_t stream) {
  const float* x  = (const float*)d_in[0];
  const int*   ei = (const int*)d_in[1];
  const float* ea = (const float*)d_in[2];
  const float* We = (const float*)d_in[3];
  const float* be = (const float*)d_in[4];
  const float* Wg = (const float*)d_in[5];
  const float* bg = (const float*)d_in[6];
  float* out = (float*)d_out;

  const size_t C_bytes = (size_t)N_NODES * 512 * 2;         // 20.48 MB
  const size_t A_bytes = (size_t)4 * N_EDGES * 16 * 2;      // 51.2 MB
  unsigned short* C = (unsigned short*)d_ws;
  const bool pre = ws_size >= C_bytes + A_bytes + 4096;     // 76.23 MB (known-satisfied)
  unsigned short* attrs_bf = pre ? (unsigned short*)((char*)d_ws + C_bytes) : nullptr;
  float* partial = (float*)((char*)d_ws + (pre ? C_bytes + A_bytes : C_bytes));

  const int grid1 = pre ? PROJ_BLOCKS + CONV_BLOCKS : PROJ_BLOCKS;
  proj_mfma<<<grid1, 256, 0, stream>>>(x, We, be, C, partial, ea, attrs_bf);
  if (pre)
    edge_mfma<true><<<EDGE_GRID, 256, 0, stream>>>(C, ei, nullptr, attrs_bf, We, partial);
  else
    edge_mfma<false><<<EDGE_GRID, 256, 0, stream>>>(C, ei, ea, nullptr, We, partial);
  graph_out<<<128, 256, 0, stream>>>(partial, Wg, bg, out);
}

// Round 9
// 268.571 us; speedup vs baseline: 1.1997x; 1.0230x over previous
//
#include <hip/hip_runtime.h>

#define N_NODES 20000
#define N_EDGES 400000
#define NODE_DIM 256
#define HIDDEN 256
#define OUT_DIM 128
#define PROJ_BLOCKS 628   // 157 m-blocks * 4 n-blocks
#define CONV_BLOCKS 1024  // conv overlaps proj in the same dispatch
#define EDGE_GRID 3125    // 25000 groups / 3125 = exactly 8 per block (no tail)
#define NPART 8           // partial-accumulator copies (atomic spreading)
#define ROWP 40           // padded LDS row stride (ushorts): 20 words, conflict-free

typedef __attribute__((ext_vector_type(8))) short short8;
typedef __attribute__((ext_vector_type(4))) float f32x4;

__device__ inline unsigned short f2bf(float f) {
  union { float f; unsigned u; } v; v.f = f;
  unsigned r = (v.u + 0x7FFFu + ((v.u >> 16) & 1u)) >> 16;
  return (unsigned short)r;
}

// ---------------- Kernel 1: bf16 MFMA proj GEMM + attrs->bf16 convert.
// C layout (bf16): C[node][half*256 + n64blk + c*4 + t] where h = n64blk + t*16 + c.
// half 0 = x@W_src, half 1 = x@W_dst + b_edge (bias folded here).
// LDS rows padded to 40 ushorts: fragment ds_read_b128 goes 8-way -> ~2-way,
// staging writes spread uniformly over banks. B staged via column-coalesced
// loads (wave reads 64 consecutive n at fixed k) + ds_write_b128 (replaces
// 16 scalar ds_write_b16 with a 16-way conflict).
__global__ __launch_bounds__(256) void proj_mfma(
    const float* __restrict__ x, const float* __restrict__ We,
    const float* __restrict__ be, unsigned short* __restrict__ C,
    float* __restrict__ partial, const float* __restrict__ attrs,
    unsigned short* __restrict__ attrs_bf) {
  const int tid = threadIdx.x;
  if (blockIdx.x >= PROJ_BLOCKS) {
    // convert attrs fp32 -> bf16 (only launched when ws has room)
    const int nt = CONV_BLOCKS * 256;
    const int total4 = 4 * N_EDGES * 16 / 4;
    for (int i = (blockIdx.x - PROJ_BLOCKS) * 256 + tid; i < total4; i += nt) {
      float4 v = ((const float4*)attrs)[i];
      ushort4 o;
      o.x = f2bf(v.x); o.y = f2bf(v.y); o.z = f2bf(v.z); o.w = f2bf(v.w);
      ((ushort4*)attrs_bf)[i] = o;
    }
    return;
  }
  if (blockIdx.x == 0) {
    for (int i = tid; i < NPART * 4 * HIDDEN; i += 256) partial[i] = 0.f;
  }
  const int bm = blockIdx.x >> 2;
  const int bn = blockIdx.x & 3;
  const int row0 = bm * 128;
  const int col0 = bn * 128;          // 0,128,256,384
  const int half = col0 >> 8;         // 0: W_src, 1: W_dst
  const int ncol0 = col0 & 255;       // 0 or 128 within half
  const int lane = tid & 63, wave = tid >> 6;
  const int q = lane >> 4, c = lane & 15;
  const int wm = wave >> 1, wn = wave & 1;

  __shared__ unsigned short As[128 * ROWP];  // [m][k], padded rows
  __shared__ unsigned short Bs[128 * ROWP];  // [n][k] (transposed W), padded rows

  f32x4 acc[4][4];
#pragma unroll
  for (int i = 0; i < 4; ++i)
#pragma unroll
    for (int t = 0; t < 4; ++t) acc[i][t] = (f32x4){0.f, 0.f, 0.f, 0.f};

  const int ar = tid >> 1;            // A stage row 0..127
  const int ak = (tid & 1) * 16;      // A stage k 0/16 (ushorts)

  for (int k0 = 0; k0 < NODE_DIM; k0 += 32) {
    {  // A: x rows -> bf16 LDS (b128 writes, uniform banks with ROWP=40)
      const int r = row0 + ar;
      short8 t0, t1;
      if (r < N_NODES) {
        const float4* src = (const float4*)&x[(size_t)r * NODE_DIM + k0 + ak];
        float4 f0 = src[0], f1 = src[1], f2 = src[2], f3 = src[3];
        t0[0]=f2bf(f0.x); t0[1]=f2bf(f0.y); t0[2]=f2bf(f0.z); t0[3]=f2bf(f0.w);
        t0[4]=f2bf(f1.x); t0[5]=f2bf(f1.y); t0[6]=f2bf(f1.z); t0[7]=f2bf(f1.w);
        t1[0]=f2bf(f2.x); t1[1]=f2bf(f2.y); t1[2]=f2bf(f2.z); t1[3]=f2bf(f2.w);
        t1[4]=f2bf(f3.x); t1[5]=f2bf(f3.y); t1[6]=f2bf(f3.z); t1[7]=f2bf(f3.w);
      } else {
#pragma unroll
        for (int j = 0; j < 8; ++j) { t0[j] = 0; t1[j] = 0; }
      }
      *(short8*)&As[ar * ROWP + ak] = t0;
      *(short8*)&As[ar * ROWP + ak + 8] = t1;
    }
    {  // B: We columns -> transposed bf16 LDS.
      // task tau = tid + 256*s covers (n, kp): 8 consecutive k at fixed n.
      // Per wave, fixed j: 64 consecutive n -> 256-B coalesced We read.
#pragma unroll
      for (int s = 0; s < 2; ++s) {
        const int tau = tid + 256 * s;
        const int kp = ((tau >> 6) & 3) * 8;            // 0,8,16,24
        const int n  = (tau & 63) + ((tau >> 8) << 6);  // 0..127
        short8 bb;
#pragma unroll
        for (int j = 0; j < 8; ++j)
          bb[j] = (short)f2bf(
              We[(size_t)(half * 256 + k0 + kp + j) * HIDDEN + ncol0 + n]);
        *(short8*)&Bs[n * ROWP + kp] = bb;
      }
    }
    __syncthreads();
    short8 Af[4], Bf[4];
#pragma unroll
    for (int i = 0; i < 4; ++i)
      Af[i] = *(const short8*)&As[(wm * 64 + i * 16 + c) * ROWP + q * 8];
#pragma unroll
    for (int t = 0; t < 4; ++t)
      Bf[t] = *(const short8*)&Bs[(wn * 64 + t * 16 + c) * ROWP + q * 8];
#pragma unroll
    for (int i = 0; i < 4; ++i)
#pragma unroll
      for (int t = 0; t < 4; ++t)
        acc[i][t] = __builtin_amdgcn_mfma_f32_16x16x32_bf16(Af[i], Bf[t], acc[i][t], 0, 0, 0);
    __syncthreads();
  }

  float biasv[4] = {0.f, 0.f, 0.f, 0.f};
  const int nbase = ncol0 + wn * 64;
  if (half) {
#pragma unroll
    for (int t = 0; t < 4; ++t) biasv[t] = be[nbase + t * 16 + c];
  }
#pragma unroll
  for (int i = 0; i < 4; ++i) {
#pragma unroll
    for (int r = 0; r < 4; ++r) {
      const int node = row0 + wm * 64 + i * 16 + q * 4 + r;
      if (node < N_NODES) {
        ushort4 o;
        o.x = f2bf(acc[i][0][r] + biasv[0]);
        o.y = f2bf(acc[i][1][r] + biasv[1]);
        o.z = f2bf(acc[i][2][r] + biasv[2]);
        o.w = f2bf(acc[i][3][r] + biasv[3]);
        *(ushort4*)&C[(size_t)node * 512 + half * 256 + nbase + c * 4] = o;
      }
    }
  }
}

// ---------------- Kernel 2: MFMA fused gather + attr-GEMM + relu + mean.
// R7 structure (folded accumulator, VGPR 60). Grid raised to 3125 so the
// freed registers turn into resident waves (more outstanding gathers);
// atomics spread over NPART partial copies to keep contention flat.
template <bool PRE>
__global__ __launch_bounds__(256) void edge_mfma(
    const unsigned short* __restrict__ C, const int* __restrict__ ei,
    const float* __restrict__ attrs_f, const unsigned short* __restrict__ attrs_b,
    const float* __restrict__ We, float* __restrict__ partial) {
  const int tid = threadIdx.x;
  const int lane = tid & 63, wave = tid >> 6;
  const int q = lane >> 4, c = lane & 15;
  const int hb = wave * 64;

  short8 Bf[4];
#pragma unroll
  for (int t = 0; t < 4; ++t) {
    short8 bf;
#pragma unroll
    for (int j = 0; j < 8; ++j) {
      int k = q * 8 + j;
      float w = (k < 16) ? We[(size_t)(512 + k) * HIDDEN + hb + t * 16 + c] : 0.0f;
      bf[j] = (short)f2bf(w);
    }
    Bf[t] = bf;
  }

  f32x4 accs[4];  // [b], component index = t  (16 accumulator regs total)
#pragma unroll
  for (int b = 0; b < 4; ++b) accs[b] = (f32x4){0.f, 0.f, 0.f, 0.f};

  const f32x4 zero4 = {0.f, 0.f, 0.f, 0.f};
  const int ngroups = N_EDGES / 16;
  for (int g = blockIdx.x; g < ngroups; g += gridDim.x) {
    const int e0 = g * 16;
    const int4 ns4 = *(const int4*)&ei[e0 + q * 4];
    const int4 nd4 = *(const int4*)&ei[N_EDGES + e0 + q * 4];

    short8 Af[4];
    if (PRE) {
      if (q < 2) {
#pragma unroll
        for (int b = 0; b < 4; ++b)
          Af[b] = *(const short8*)&attrs_b[((size_t)b * N_EDGES + e0 + c) * 16 + q * 8];
      } else {
        short8 z;
#pragma unroll
        for (int j = 0; j < 8; ++j) z[j] = 0;
#pragma unroll
        for (int b = 0; b < 4; ++b) Af[b] = z;
      }
    } else {
      if (q < 2) {
#pragma unroll
        for (int b = 0; b < 4; ++b) {
          const size_t off = ((size_t)b * N_EDGES + e0 + c) * 16 + q * 8;
          const float4 a0 = *(const float4*)&attrs_f[off];
          const float4 a1 = *(const float4*)&attrs_f[off + 4];
          short8 af;
          af[0]=f2bf(a0.x); af[1]=f2bf(a0.y); af[2]=f2bf(a0.z); af[3]=f2bf(a0.w);
          af[4]=f2bf(a1.x); af[5]=f2bf(a1.y); af[6]=f2bf(a1.z); af[7]=f2bf(a1.w);
          Af[b] = af;
        }
      } else {
        short8 z;
#pragma unroll
        for (int j = 0; j < 8; ++j) z[j] = 0;
#pragma unroll
        for (int b = 0; b < 4; ++b) Af[b] = z;
      }
    }

    f32x4 base4[4];  // [t], component = row r (bias already folded into dst half)
    {
      const int nn[4] = {ns4.x, ns4.y, ns4.z, ns4.w};
      const int dd[4] = {nd4.x, nd4.y, nd4.z, nd4.w};
#pragma unroll
      for (int r = 0; r < 4; ++r) {
        const uint2 s = *(const uint2*)&C[(size_t)nn[r] * 512 + hb + c * 4];
        const uint2 d = *(const uint2*)&C[(size_t)dd[r] * 512 + 256 + hb + c * 4];
        base4[0][r] = __uint_as_float(s.x << 16) + __uint_as_float(d.x << 16);
        base4[1][r] = __uint_as_float(s.x & 0xFFFF0000u) + __uint_as_float(d.x & 0xFFFF0000u);
        base4[2][r] = __uint_as_float(s.y << 16) + __uint_as_float(d.y << 16);
        base4[3][r] = __uint_as_float(s.y & 0xFFFF0000u) + __uint_as_float(d.y & 0xFFFF0000u);
      }
    }

#pragma unroll
    for (int b = 0; b < 4; ++b) {
#pragma unroll
      for (int t = 0; t < 4; ++t) {
        f32x4 S = __builtin_amdgcn_mfma_f32_16x16x32_bf16(Af[b], Bf[t], zero4, 0, 0, 0);
        f32x4 u = S + base4[t];
        u[0] = fmaxf(u[0], 0.f); u[1] = fmaxf(u[1], 0.f);
        u[2] = fmaxf(u[2], 0.f); u[3] = fmaxf(u[3], 0.f);
        // fold the 4 edges (rows r) of this q-group into one scalar now:
        accs[b][t] += (u[0] + u[1]) + (u[2] + u[3]);
      }
    }
  }

  float* pp = partial + (size_t)(blockIdx.x & (NPART - 1)) * (4 * HIDDEN);
#pragma unroll
  for (int b = 0; b < 4; ++b)
#pragma unroll
    for (int t = 0; t < 4; ++t) {
      float v = accs[b][t];
      v += __shfl_xor(v, 16, 64);
      v += __shfl_xor(v, 32, 64);
      if (q == 0) atomicAdd(&pp[b * HIDDEN + hb + t * 16 + c], v);
    }
}

// ---------------- Kernel 3: out[b,o] = (S[b,:]/E) @ W_graph + b_graph
__global__ __launch_bounds__(256) void graph_out(
    const float* __restrict__ partial, const float* __restrict__ Wg,
    const float* __restrict__ bg, float* __restrict__ out) {
  const int o = blockIdx.x;    // 0..127
  const int hh = threadIdx.x;  // 0..255
  const int lane = hh & 63, wave = hh >> 6;
  const float w = Wg[(size_t)hh * OUT_DIM + o];
  float v[4];
#pragma unroll
  for (int b = 0; b < 4; ++b) {
    float s = 0.f;
#pragma unroll
    for (int k = 0; k < NPART; ++k) s += partial[k * 4 * HIDDEN + b * HIDDEN + hh];
    v[b] = s * w;
  }
#pragma unroll
  for (int off = 32; off >= 1; off >>= 1)
#pragma unroll
    for (int b = 0; b < 4; ++b) v[b] += __shfl_down(v[b], off, 64);
  __shared__ float red[4][4];
  if (lane == 0)
#pragma unroll
    for (int b = 0; b < 4; ++b) red[wave][b] = v[b];
  __syncthreads();
  if (hh < 4) {
    float s = red[0][hh] + red[1][hh] + red[2][hh] + red[3][hh];
    out[hh * OUT_DIM + o] = s * (1.0f / (float)N_EDGES) + bg[o];
  }
}

extern "C" void kernel_launch(void* const* d_in, const int* in_sizes, int n_in,
                              void* d_out, int out_size, void* d_ws, size_t ws_size,
                              hipStream_t stream) {
  const float* x  = (const float*)d_in[0];
  const int*   ei = (const int*)d_in[1];
  const float* ea = (const float*)d_in[2];
  const float* We = (const float*)d_in[3];
  const float* be = (const float*)d_in[4];
  const float* Wg = (const float*)d_in[5];
  const float* bg = (const float*)d_in[6];
  float* out = (float*)d_out;

  const size_t C_bytes = (size_t)N_NODES * 512 * 2;         // 20.48 MB
  const size_t A_bytes = (size_t)4 * N_EDGES * 16 * 2;      // 51.2 MB
  const size_t P_bytes = (size_t)NPART * 4 * HIDDEN * 4;    // 32 KB
  unsigned short* C = (unsigned short*)d_ws;
  const bool pre = ws_size >= C_bytes + A_bytes + P_bytes + 4096;
  unsigned short* attrs_bf = pre ? (unsigned short*)((char*)d_ws + C_bytes) : nullptr;
  float* partial = (float*)((char*)d_ws + (pre ? C_bytes + A_bytes : C_bytes));

  const int grid1 = pre ? PROJ_BLOCKS + CONV_BLOCKS : PROJ_BLOCKS;
  proj_mfma<<<grid1, 256, 0, stream>>>(x, We, be, C, partial, ea, attrs_bf);
  if (pre)
    edge_mfma<true><<<EDGE_GRID, 256, 0, stream>>>(C, ei, nullptr, attrs_bf, We, partial);
  else
    edge_mfma<false><<<EDGE_GRID, 256, 0, stream>>>(C, ei, ea, nullptr, We, partial);
  graph_out<<<128, 256, 0, stream>>>(partial, Wg, bg, out);
}

// Round 10
// 262.296 us; speedup vs baseline: 1.2284x; 1.0239x over previous
//
#include <hip/hip_runtime.h>

#define N_NODES 20000
#define N_EDGES 400000
#define NODE_DIM 256
#define HIDDEN 256
#define OUT_DIM 128
#define PROJ_BLOCKS 628   // 157 m-blocks * 4 n-blocks
#define CONV_BLOCKS 1024  // conv overlaps proj in the same dispatch
#define EDGE_GRID 3125    // 25000 groups / 3125 = exactly 8 per block (no tail)
#define NPART 8           // partial-accumulator copies (atomic spreading)
#define ROWP 40           // padded LDS row stride (ushorts)

typedef __attribute__((ext_vector_type(8))) short short8;
typedef __attribute__((ext_vector_type(4))) short bf16x4;
typedef __attribute__((ext_vector_type(4))) float f32x4;

__device__ inline unsigned short f2bf(float f) {
  union { float f; unsigned u; } v; v.f = f;
  unsigned r = (v.u + 0x7FFFu + ((v.u >> 16) & 1u)) >> 16;
  return (unsigned short)r;
}

// ---------------- Kernel 1: bf16 MFMA proj GEMM + attrs->bf16 convert.
// (byte-identical to round 9 — passed, counters stable)
__global__ __launch_bounds__(256) void proj_mfma(
    const float* __restrict__ x, const float* __restrict__ We,
    const float* __restrict__ be, unsigned short* __restrict__ C,
    float* __restrict__ partial, const float* __restrict__ attrs,
    unsigned short* __restrict__ attrs_bf) {
  const int tid = threadIdx.x;
  if (blockIdx.x >= PROJ_BLOCKS) {
    const int nt = CONV_BLOCKS * 256;
    const int total4 = 4 * N_EDGES * 16 / 4;
    for (int i = (blockIdx.x - PROJ_BLOCKS) * 256 + tid; i < total4; i += nt) {
      float4 v = ((const float4*)attrs)[i];
      ushort4 o;
      o.x = f2bf(v.x); o.y = f2bf(v.y); o.z = f2bf(v.z); o.w = f2bf(v.w);
      ((ushort4*)attrs_bf)[i] = o;
    }
    return;
  }
  if (blockIdx.x == 0) {
    for (int i = tid; i < NPART * 4 * HIDDEN; i += 256) partial[i] = 0.f;
  }
  const int bm = blockIdx.x >> 2;
  const int bn = blockIdx.x & 3;
  const int row0 = bm * 128;
  const int col0 = bn * 128;
  const int half = col0 >> 8;
  const int ncol0 = col0 & 255;
  const int lane = tid & 63, wave = tid >> 6;
  const int q = lane >> 4, c = lane & 15;
  const int wm = wave >> 1, wn = wave & 1;

  __shared__ unsigned short As[128 * ROWP];
  __shared__ unsigned short Bs[128 * ROWP];

  f32x4 acc[4][4];
#pragma unroll
  for (int i = 0; i < 4; ++i)
#pragma unroll
    for (int t = 0; t < 4; ++t) acc[i][t] = (f32x4){0.f, 0.f, 0.f, 0.f};

  const int ar = tid >> 1;
  const int ak = (tid & 1) * 16;

  for (int k0 = 0; k0 < NODE_DIM; k0 += 32) {
    {
      const int r = row0 + ar;
      short8 t0, t1;
      if (r < N_NODES) {
        const float4* src = (const float4*)&x[(size_t)r * NODE_DIM + k0 + ak];
        float4 f0 = src[0], f1 = src[1], f2 = src[2], f3 = src[3];
        t0[0]=f2bf(f0.x); t0[1]=f2bf(f0.y); t0[2]=f2bf(f0.z); t0[3]=f2bf(f0.w);
        t0[4]=f2bf(f1.x); t0[5]=f2bf(f1.y); t0[6]=f2bf(f1.z); t0[7]=f2bf(f1.w);
        t1[0]=f2bf(f2.x); t1[1]=f2bf(f2.y); t1[2]=f2bf(f2.z); t1[3]=f2bf(f2.w);
        t1[4]=f2bf(f3.x); t1[5]=f2bf(f3.y); t1[6]=f2bf(f3.z); t1[7]=f2bf(f3.w);
      } else {
#pragma unroll
        for (int j = 0; j < 8; ++j) { t0[j] = 0; t1[j] = 0; }
      }
      *(short8*)&As[ar * ROWP + ak] = t0;
      *(short8*)&As[ar * ROWP + ak + 8] = t1;
    }
    {
#pragma unroll
      for (int s = 0; s < 2; ++s) {
        const int tau = tid + 256 * s;
        const int kp = ((tau >> 6) & 3) * 8;
        const int n  = (tau & 63) + ((tau >> 8) << 6);
        short8 bb;
#pragma unroll
        for (int j = 0; j < 8; ++j)
          bb[j] = (short)f2bf(
              We[(size_t)(half * 256 + k0 + kp + j) * HIDDEN + ncol0 + n]);
        *(short8*)&Bs[n * ROWP + kp] = bb;
      }
    }
    __syncthreads();
    short8 Af[4], Bf[4];
#pragma unroll
    for (int i = 0; i < 4; ++i)
      Af[i] = *(const short8*)&As[(wm * 64 + i * 16 + c) * ROWP + q * 8];
#pragma unroll
    for (int t = 0; t < 4; ++t)
      Bf[t] = *(const short8*)&Bs[(wn * 64 + t * 16 + c) * ROWP + q * 8];
#pragma unroll
    for (int i = 0; i < 4; ++i)
#pragma unroll
      for (int t = 0; t < 4; ++t)
        acc[i][t] = __builtin_amdgcn_mfma_f32_16x16x32_bf16(Af[i], Bf[t], acc[i][t], 0, 0, 0);
    __syncthreads();
  }

  float biasv[4] = {0.f, 0.f, 0.f, 0.f};
  const int nbase = ncol0 + wn * 64;
  if (half) {
#pragma unroll
    for (int t = 0; t < 4; ++t) biasv[t] = be[nbase + t * 16 + c];
  }
#pragma unroll
  for (int i = 0; i < 4; ++i) {
#pragma unroll
    for (int r = 0; r < 4; ++r) {
      const int node = row0 + wm * 64 + i * 16 + q * 4 + r;
      if (node < N_NODES) {
        ushort4 o;
        o.x = f2bf(acc[i][0][r] + biasv[0]);
        o.y = f2bf(acc[i][1][r] + biasv[1]);
        o.z = f2bf(acc[i][2][r] + biasv[2]);
        o.w = f2bf(acc[i][3][r] + biasv[3]);
        *(ushort4*)&C[(size_t)node * 512 + half * 256 + nbase + c * 4] = o;
      }
    }
  }
}

// ---------------- Kernel 2: MFMA fused gather + attr-GEMM + relu + mean.
// R9 structure with two changes:
//  (a) 16x16x16 bf16 MFMA (K = EDGE_DIM exactly): no zero-padded K half,
//      no divergent q<2 branch, all 64 lanes load 8 B of real attrs
//      (tiles exactly 512 B per b per wave). A: lane=edge c, k=q*4..+3.
//      Same C/D layout as 16x16x32 (shape-determined) -> epilogue unchanged.
//  (b) edge indices prefetched 1 iteration ahead (breaks ei->gather chain).
template <bool PRE>
__global__ __launch_bounds__(256) void edge_mfma(
    const unsigned short* __restrict__ C, const int* __restrict__ ei,
    const float* __restrict__ attrs_f, const unsigned short* __restrict__ attrs_b,
    const float* __restrict__ We, float* __restrict__ partial) {
  const int tid = threadIdx.x;
  const int lane = tid & 63, wave = tid >> 6;
  const int q = lane >> 4, c = lane & 15;
  const int q4 = q * 4;
  const int hb = wave * 64;

  bf16x4 Bf[4];  // B operand: n = hb + t*16 + c, k = q4 + j
#pragma unroll
  for (int t = 0; t < 4; ++t) {
    bf16x4 bf;
#pragma unroll
    for (int j = 0; j < 4; ++j)
      bf[j] = (short)f2bf(We[(size_t)(512 + q4 + j) * HIDDEN + hb + t * 16 + c]);
    Bf[t] = bf;
  }

  f32x4 accs[4];  // [b], component index = t
#pragma unroll
  for (int b = 0; b < 4; ++b) accs[b] = (f32x4){0.f, 0.f, 0.f, 0.f};

  const f32x4 zero4 = {0.f, 0.f, 0.f, 0.f};
  const int ngroups = N_EDGES / 16;

  // prologue: indices for the first group
  int4 ns4 = *(const int4*)&ei[blockIdx.x * 16 + q * 4];
  int4 nd4 = *(const int4*)&ei[N_EDGES + blockIdx.x * 16 + q * 4];

  for (int g = blockIdx.x; g < ngroups; g += gridDim.x) {
    const int e0 = g * 16;
    const int gn = g + gridDim.x;

    // gathers first (indices already in regs)
    uint2 sv[4], dv[4];
    {
      const int nn[4] = {ns4.x, ns4.y, ns4.z, ns4.w};
      const int dd[4] = {nd4.x, nd4.y, nd4.z, nd4.w};
#pragma unroll
      for (int r = 0; r < 4; ++r) {
        sv[r] = *(const uint2*)&C[(size_t)nn[r] * 512 + hb + c * 4];
        dv[r] = *(const uint2*)&C[(size_t)dd[r] * 512 + 256 + hb + c * 4];
      }
    }
    // prefetch next group's indices
    if (gn < ngroups) {
      ns4 = *(const int4*)&ei[gn * 16 + q * 4];
      nd4 = *(const int4*)&ei[N_EDGES + gn * 16 + q * 4];
    }

    // attrs: A operand, 8 B per lane, all lanes real data
    bf16x4 Af[4];
    if (PRE) {
#pragma unroll
      for (int b = 0; b < 4; ++b)
        Af[b] = *(const bf16x4*)&attrs_b[((size_t)b * N_EDGES + e0 + c) * 16 + q4];
    } else {
#pragma unroll
      for (int b = 0; b < 4; ++b) {
        const size_t off = ((size_t)b * N_EDGES + e0 + c) * 16 + q4;
        const float4 a0 = *(const float4*)&attrs_f[off];
        bf16x4 af;
        af[0]=f2bf(a0.x); af[1]=f2bf(a0.y); af[2]=f2bf(a0.z); af[3]=f2bf(a0.w);
        Af[b] = af;
      }
    }

    // unpack base = src + dst (bias already folded into dst half)
    f32x4 base4[4];  // [t], component = row r
#pragma unroll
    for (int r = 0; r < 4; ++r) {
      const uint2 s = sv[r], d = dv[r];
      base4[0][r] = __uint_as_float(s.x << 16) + __uint_as_float(d.x << 16);
      base4[1][r] = __uint_as_float(s.x & 0xFFFF0000u) + __uint_as_float(d.x & 0xFFFF0000u);
      base4[2][r] = __uint_as_float(s.y << 16) + __uint_as_float(d.y << 16);
      base4[3][r] = __uint_as_float(s.y & 0xFFFF0000u) + __uint_as_float(d.y & 0xFFFF0000u);
    }

#pragma unroll
    for (int b = 0; b < 4; ++b) {
#pragma unroll
      for (int t = 0; t < 4; ++t) {
        f32x4 S = __builtin_amdgcn_mfma_f32_16x16x16bf16_1k(Af[b], Bf[t], zero4, 0, 0, 0);
        f32x4 u = S + base4[t];
        u[0] = fmaxf(u[0], 0.f); u[1] = fmaxf(u[1], 0.f);
        u[2] = fmaxf(u[2], 0.f); u[3] = fmaxf(u[3], 0.f);
        accs[b][t] += (u[0] + u[1]) + (u[2] + u[3]);
      }
    }
  }

  float* pp = partial + (size_t)(blockIdx.x & (NPART - 1)) * (4 * HIDDEN);
#pragma unroll
  for (int b = 0; b < 4; ++b)
#pragma unroll
    for (int t = 0; t < 4; ++t) {
      float v = accs[b][t];
      v += __shfl_xor(v, 16, 64);
      v += __shfl_xor(v, 32, 64);
      if (q == 0) atomicAdd(&pp[b * HIDDEN + hb + t * 16 + c], v);
    }
}

// ---------------- Kernel 3: out[b,o] = (S[b,:]/E) @ W_graph + b_graph
__global__ __launch_bounds__(256) void graph_out(
    const float* __restrict__ partial, const float* __restrict__ Wg,
    const float* __restrict__ bg, float* __restrict__ out) {
  const int o = blockIdx.x;
  const int hh = threadIdx.x;
  const int lane = hh & 63, wave = hh >> 6;
  const float w = Wg[(size_t)hh * OUT_DIM + o];
  float v[4];
#pragma unroll
  for (int b = 0; b < 4; ++b) {
    float s = 0.f;
#pragma unroll
    for (int k = 0; k < NPART; ++k) s += partial[k * 4 * HIDDEN + b * HIDDEN + hh];
    v[b] = s * w;
  }
#pragma unroll
  for (int off = 32; off >= 1; off >>= 1)
#pragma unroll
    for (int b = 0; b < 4; ++b) v[b] += __shfl_down(v[b], off, 64);
  __shared__ float red[4][4];
  if (lane == 0)
#pragma unroll
    for (int b = 0; b < 4; ++b) red[wave][b] = v[b];
  __syncthreads();
  if (hh < 4) {
    float s = red[0][hh] + red[1][hh] + red[2][hh] + red[3][hh];
    out[hh * OUT_DIM + o] = s * (1.0f / (float)N_EDGES) + bg[o];
  }
}

extern "C" void kernel_launch(void* const* d_in, const int* in_sizes, int n_in,
                              void* d_out, int out_size, void* d_ws, size_t ws_size,
                              hipStream_t stream) {
  const float* x  = (const float*)d_in[0];
  const int*   ei = (const int*)d_in[1];
  const float* ea = (const float*)d_in[2];
  const float* We = (const float*)d_in[3];
  const float* be = (const float*)d_in[4];
  const float* Wg = (const float*)d_in[5];
  const float* bg = (const float*)d_in[6];
  float* out = (float*)d_out;

  const size_t C_bytes = (size_t)N_NODES * 512 * 2;         // 20.48 MB
  const size_t A_bytes = (size_t)4 * N_EDGES * 16 * 2;      // 51.2 MB
  const size_t P_bytes = (size_t)NPART * 4 * HIDDEN * 4;    // 32 KB
  unsigned short* C = (unsigned short*)d_ws;
  const bool pre = ws_size >= C_bytes + A_bytes + P_bytes + 4096;
  unsigned short* attrs_bf = pre ? (unsigned short*)((char*)d_ws + C_bytes) : nullptr;
  float* partial = (float*)((char*)d_ws + (pre ? C_bytes + A_bytes : C_bytes));

  const int grid1 = pre ? PROJ_BLOCKS + CONV_BLOCKS : PROJ_BLOCKS;
  proj_mfma<<<grid1, 256, 0, stream>>>(x, We, be, C, partial, ea, attrs_bf);
  if (pre)
    edge_mfma<true><<<EDGE_GRID, 256, 0, stream>>>(C, ei, nullptr, attrs_bf, We, partial);
  else
    edge_mfma<false><<<EDGE_GRID, 256, 0, stream>>>(C, ei, ea, nullptr, We, partial);
  graph_out<<<128, 256, 0, stream>>>(partial, Wg, bg, out);
}